// Round 4
// baseline (47.072 us; speedup 1.0000x reference)
//
#include <hip/hip_runtime.h>

#define NUM_FREQ 32
#define KU 8  // float4 elements per thread

typedef float vfloat4 __attribute__((ext_vector_type(4)));

// Fully fused, barrier-free streaming kernel.
// Each block of 256 threads handles 2048 consecutive float4 (= 64 sp-rows),
// which provably share one (b,c)  (2048/32 = 64 sp, 64 | 512 with aligned
// start => single c; 64 | 65536 => single b).
// Every lane builds its OWN combined matrix M[f], f = t&31, entirely in
// registers: no LDS, no __syncthreads, so the compiler can pipeline the 8
// streaming loads with descending vmcnt waits instead of a full barrier drain.
__global__ void __launch_bounds__(256)
camfreq_fused_kernel(const vfloat4* __restrict__ feats,
                     const float* __restrict__ matrix,
                     const float* __restrict__ L_params,
                     const float* __restrict__ D_params,
                     const float* __restrict__ U_params,
                     vfloat4* __restrict__ out) {
    const int t    = threadIdx.x;
    const int base = blockIdx.x * (256 * KU);   // float4 index base

    // Wave-uniform (b,c) for the whole block.
    const int sp0 = base >> 5;        // (b*16+n)*4096 + s
    const int s0  = sp0 & 4095;
    const int b   = sp0 >> 16;
    const int c   = s0 >> 9;

    // Issue all streaming loads first: HBM latency hides under the M build.
    vfloat4 v[KU];
#pragma unroll
    for (int k = 0; k < KU; ++k) {
        v[k] = __builtin_nontemporal_load(&feats[base + k * 256 + t]);
    }

    // Per-lane build of M = (L_f diag(e^D_f) U_f) @ matrix[b,c], f = t&31.
    const int f = t & (NUM_FREQ - 1);
    const float l0 = L_params[f * 6 + 0], l1 = L_params[f * 6 + 1];
    const float l2 = L_params[f * 6 + 2], l3 = L_params[f * 6 + 3];
    const float l4 = L_params[f * 6 + 4], l5 = L_params[f * 6 + 5];
    const float e0 = __expf(D_params[f * 4 + 0]);
    const float e1 = __expf(D_params[f * 4 + 1]);
    const float e2 = __expf(D_params[f * 4 + 2]);
    const float e3 = __expf(D_params[f * 4 + 3]);
    const float u0 = U_params[f * 6 + 0], u1 = U_params[f * 6 + 1];
    const float u2 = U_params[f * 6 + 2], u3 = U_params[f * 6 + 3];
    const float u4 = U_params[f * 6 + 4], u5 = U_params[f * 6 + 5];

    // freq[i][k] = sum_j L[i][j]*e[j]*U[j][k]
    float fr[4][4];
    fr[0][0] = e0;      fr[0][1] = e0 * u0;  fr[0][2] = e0 * u1;            fr[0][3] = e0 * u2;
    fr[1][0] = l0 * e0;
    fr[1][1] = l0 * e0 * u0 + e1;
    fr[1][2] = l0 * e0 * u1 + e1 * u3;
    fr[1][3] = l0 * e0 * u2 + e1 * u4;
    fr[2][0] = l1 * e0;
    fr[2][1] = l1 * e0 * u0 + l2 * e1;
    fr[2][2] = l1 * e0 * u1 + l2 * e1 * u3 + e2;
    fr[2][3] = l1 * e0 * u2 + l2 * e1 * u4 + e2 * u5;
    fr[3][0] = l3 * e0;
    fr[3][1] = l3 * e0 * u0 + l4 * e1;
    fr[3][2] = l3 * e0 * u1 + l4 * e1 * u3 + l5 * e2;
    fr[3][3] = l3 * e0 * u2 + l4 * e1 * u4 + l5 * e2 * u5 + e3;

    // M = fr @ matrix[b,c]  (matrix is wave-uniform -> scalar loads).
    const float* mt = matrix + ((b << 3) + c) * 16;
    float M[4][4];
#pragma unroll
    for (int i = 0; i < 4; ++i) {
#pragma unroll
        for (int k = 0; k < 4; ++k) {
            M[i][k] = fr[i][0] * mt[0 * 4 + k]
                    + fr[i][1] * mt[1 * 4 + k]
                    + fr[i][2] * mt[2 * 4 + k]
                    + fr[i][3] * mt[3 * 4 + k];
        }
    }

    // Stream: per-k matvec + nontemporal store (compiler pipelines vmcnt).
#pragma unroll
    for (int k = 0; k < KU; ++k) {
        vfloat4 o;
        o.x = M[0][0] * v[k].x + M[0][1] * v[k].y + M[0][2] * v[k].z + M[0][3] * v[k].w;
        o.y = M[1][0] * v[k].x + M[1][1] * v[k].y + M[1][2] * v[k].z + M[1][3] * v[k].w;
        o.z = M[2][0] * v[k].x + M[2][1] * v[k].y + M[2][2] * v[k].z + M[2][3] * v[k].w;
        o.w = M[3][0] * v[k].x + M[3][1] * v[k].y + M[3][2] * v[k].z + M[3][3] * v[k].w;
        __builtin_nontemporal_store(o, &out[base + k * 256 + t]);
    }
}

extern "C" void kernel_launch(void* const* d_in, const int* in_sizes, int n_in,
                              void* d_out, int out_size, void* d_ws, size_t ws_size,
                              hipStream_t stream) {
    const float* feats    = (const float*)d_in[0];
    const float* matrix   = (const float*)d_in[1];
    const float* L_params = (const float*)d_in[2];
    const float* D_params = (const float*)d_in[3];
    const float* U_params = (const float*)d_in[4];
    float* out = (float*)d_out;

    const int total4 = (4 * 16 * 4096 * 128) / 4;   // 8,388,608 float4
    const int block  = 256;
    const int grid   = total4 / (block * KU);       // 4096 blocks
    camfreq_fused_kernel<<<grid, block, 0, stream>>>(
        reinterpret_cast<const vfloat4*>(feats), matrix, L_params, D_params,
        U_params, reinterpret_cast<vfloat4*>(out));
}